// Round 6
// baseline (39.677 us; speedup 1.0000x reference)
//
#include <hip/hip_runtime.h>
#include <hip/hip_bf16.h>

// Shapes (fixed): D=1, S=64, A=128, P=K=6, T=80
#define NS 64
#define NA 128
#define NK 6
#define NT 80
#define THREADS 256

// Output layout (flat concat, float):
//   waymo_valid  [S,T,A]        655360
//   waymo_trajs  [S,T,A,K,2]    7864320
//   waymo_scores [S,A,K]        49152
//   waymo_yaw    [S,T,A,K,1]    3932160
#define OFF_TRAJ   655360
#define OFF_SCORE  (655360 + 7864320)
#define OFF_YAW    (655360 + 7864320 + 49152)

// pos role: 4 agents (24 rows), LDS float2[24*81] = 15552 B
#define PA 4
#define PROWS (PA * NK)      // 24
#define PSTRIDE 81           // float2 units (odd -> 8-residue bank spread on col reads)
// yaw role: 8 agents (48 rows), LDS float[48*85] = 16320 B
#define YA 8
#define YROWS (YA * NK)      // 48
#define YSTRIDE 85           // float units (odd)

#define NPB (NS * (NA / PA))   // 2048 pos blocks
#define NYB (NS * (NA / YA))   // 1024 yaw blocks

typedef float nfloat4 __attribute__((ext_vector_type(4)));

__global__ __launch_bounds__(THREADS) void waymo_post_kernel(
    const int*    __restrict__ validIn,  // [S,A] (bool -> int32)
    const float*  __restrict__ confIn,   // [1,S,A,K]
    const float2* __restrict__ posIn,    // [1,S,A,K,T] float2
    const float*  __restrict__ yawIn,    // [1,S,A,K,T]
    const float*  __restrict__ typeIn,   // [S,A,3] one-hot
    float*        __restrict__ out)
{
    const int g   = blockIdx.x;
    const int tid = threadIdx.x;

    __shared__ float smem[YROWS * YSTRIDE];  // 16320 B (max of both roles)

    float* outSc = out + OFF_SCORE;

    // role interleave: g%3==2 -> yaw block, else pos block
    const int e = g % 3;
    if (e != 2) {
        // ======================= POS ROLE (score + traj) =======================
        const int pb = (g / 3) * 2 + e;            // 0..2047
        const int s  = pb >> 5;
        const int a0 = (pb & 31) * PA;

        float2* P = (float2*)smem;
        const size_t sa0 = (size_t)s * NA + a0;
        const float2* pbase = posIn + sa0 * (NK * NT);

        // stage: 24 rows x 40 float4 = 960 loads, contiguous 15 KB range
        for (int i = tid; i < PROWS * (NT / 2); i += THREADS) {
            int r = i / 40, q = i - r * 40;
            nfloat4 v = __builtin_nontemporal_load((const nfloat4*)(pbase + (size_t)r * NT + 2 * q));
            P[r * PSTRIDE + 2 * q + 0] = float2{v.x, v.y};
            P[r * PSTRIDE + 2 * q + 1] = float2{v.z, v.w};
        }
        __syncthreads();

        // ---- score + NMS: waves 0..1 (32 lanes/agent, 4 agents) ----
        if (tid < 32 * PA) {
            const int la   = tid >> 5;
            const int lane = tid & 31;
            const int a    = a0 + la;
            const int p    = lane >> 1;   // pair slot 0..15 (15 used)
            const int half = lane & 1;    // time half

            const size_t sa = (size_t)s * NA + a;
            const float th = 2.5f * typeIn[sa * 3 + 0]
                           + 1.0f * typeIn[sa * 3 + 1]
                           + 1.5f * typeIn[sa * 3 + 2];

            int pi, pj;
            if      (p < 5)  { pi = 0; pj = p + 1; }
            else if (p < 9)  { pi = 1; pj = p - 3; }
            else if (p < 12) { pi = 2; pj = p - 6; }
            else if (p < 14) { pi = 3; pj = p - 8; }
            else             { pi = 4; pj = 5;     }

            const int rI = la * NK + pi, rJ = la * NK + pj;
            float dsum = 0.f;
            for (int t = half * 40; t < half * 40 + 40; ++t) {
                float2 u = P[rI * PSTRIDE + t];
                float2 v = P[rJ * PSTRIDE + t];
                float dx = u.x - v.x, dy = u.y - v.y;
                dsum += sqrtf(dx * dx + dy * dy);
            }
            dsum += __shfl_xor(dsum, 1);
            const bool within = (dsum / 80.0f) < th;
            const bool predb  = (half == 0) && (p < 15) && within;
            unsigned long long bal = __ballot(predb);
            unsigned mask32 = (unsigned)(bal >> (tid & 32));

            if (lane == 0) {
                float c[NK];
                float mx = -3e38f;
                for (int q = 0; q < NK; ++q) { c[q] = confIn[sa * NK + q]; mx = fmaxf(mx, c[q]); }
                float ssum = 0.f;
                for (int q = 0; q < NK; ++q) { c[q] = expf(c[q] - mx); ssum += c[q]; }
                for (int q = 0; q < NK; ++q) c[q] /= ssum;
                ssum = 0.f;
                for (int q = 0; q < NK; ++q) ssum += c[q];
                for (int q = 0; q < NK; ++q) c[q] /= ssum;

                int ord[NK]; bool used[NK];
                for (int q = 0; q < NK; ++q) used[q] = false;
                for (int st = 0; st < NK; ++st) {
                    int best = 0; float bv = -3e38f;
                    for (int q = 0; q < NK; ++q)
                        if (!used[q] && c[q] > bv) { bv = c[q]; best = q; }
                    used[best] = true; ord[st] = best;
                }

                float cur[NK];
                for (int q = 0; q < NK; ++q) cur[q] = c[q];

                if (validIn[sa] != 0) {
                    for (int st = 0; st < NK; ++st) {
                        int k = ord[st];
                        float ck = cur[k];
                        bool any = false;
                        for (int j = 0; j < NK; ++j) {
                            if (j == k) continue;
                            int lo = j < k ? j : k;
                            int hi = j < k ? k : j;
                            int pidx = lo * 5 - (lo * (lo - 1)) / 2 + (hi - lo - 1);
                            if (((mask32 >> (2 * pidx)) & 1u) && (cur[j] > ck)) any = true;
                        }
                        if (any) cur[k] = 0.001f;
                    }
                }

                float tsum = 0.f;
                for (int q = 0; q < NK; ++q) tsum += cur[q];
                float w[NK]; float wsum = 0.f;
                for (int q = 0; q < NK; ++q) {
                    float qq = cur[q] / tsum;
                    w[q] = qq * qq; wsum += w[q];
                }
                for (int q = 0; q < NK; ++q) outSc[sa * NK + q] = w[q] / wsum;
            }
        }

        // ---- traj out: per t, 24 rows (float2) -> 12 float4, 960 stores ----
        nfloat4* trajOut = (nfloat4*)(out + OFF_TRAJ);
        for (int o = tid; o < NT * 12; o += THREADS) {
            int t = o / 12, j = o - (o / 12) * 12;
            float2 u = P[(2 * j + 0) * PSTRIDE + t];
            float2 w = P[(2 * j + 1) * PSTRIDE + t];
            nfloat4 v{u.x, u.y, w.x, w.y};
            size_t f4 = (((size_t)(s * NT + t) * NA + a0) * NK) >> 1;
            __builtin_nontemporal_store(v, trajOut + f4 + j);
        }
    } else {
        // ======================= YAW ROLE (yaw + valid) =======================
        const int yb = g / 3;                      // 0..1023
        const int s  = yb >> 4;
        const int a0 = (yb & 15) * YA;

        float* Y = smem;
        const size_t sa0 = (size_t)s * NA + a0;
        const float* ybase = yawIn + sa0 * (NK * NT);

        // valid out first (no LDS dependency): per t, 8 agents -> 2 float4
        if (tid < 160) {
            int t = tid >> 1, q = tid & 1;
            nfloat4 v;
            v.x = (validIn[sa0 + 4 * q + 0] != 0) ? 1.0f : 0.0f;
            v.y = (validIn[sa0 + 4 * q + 1] != 0) ? 1.0f : 0.0f;
            v.z = (validIn[sa0 + 4 * q + 2] != 0) ? 1.0f : 0.0f;
            v.w = (validIn[sa0 + 4 * q + 3] != 0) ? 1.0f : 0.0f;
            size_t f4 = ((size_t)(s * NT + t) * NA + a0) >> 2;
            __builtin_nontemporal_store(v, (nfloat4*)out + f4 + q);
        }

        // stage: 48 rows x 20 float4 = 960 loads, contiguous 15 KB range
        for (int i = tid; i < YROWS * (NT / 4); i += THREADS) {
            int r = i / 20, m = i - r * 20;
            nfloat4 v = __builtin_nontemporal_load((const nfloat4*)(ybase + (size_t)r * NT + 4 * m));
            Y[r * YSTRIDE + 4 * m + 0] = v.x;
            Y[r * YSTRIDE + 4 * m + 1] = v.y;
            Y[r * YSTRIDE + 4 * m + 2] = v.z;
            Y[r * YSTRIDE + 4 * m + 3] = v.w;
        }
        __syncthreads();

        // yaw out: per t, 48 rows (float) -> 12 float4, 960 stores
        nfloat4* yawOut = (nfloat4*)(out + OFF_YAW);
        for (int o = tid; o < NT * 12; o += THREADS) {
            int t = o / 12, j = o - (o / 12) * 12;
            nfloat4 v{Y[(4 * j + 0) * YSTRIDE + t],
                      Y[(4 * j + 1) * YSTRIDE + t],
                      Y[(4 * j + 2) * YSTRIDE + t],
                      Y[(4 * j + 3) * YSTRIDE + t]};
            size_t f4 = (((size_t)(s * NT + t) * NA + a0) * NK) >> 2;
            __builtin_nontemporal_store(v, yawOut + f4 + j);
        }
    }
}

extern "C" void kernel_launch(void* const* d_in, const int* in_sizes, int n_in,
                              void* d_out, int out_size, void* d_ws, size_t ws_size,
                              hipStream_t stream) {
    const int*    validIn = (const int*)d_in[0];
    const float*  confIn  = (const float*)d_in[1];
    const float2* posIn   = (const float2*)d_in[2];
    const float*  yawIn   = (const float*)d_in[3];
    const float*  typeIn  = (const float*)d_in[4];
    float* out = (float*)d_out;

    waymo_post_kernel<<<NPB + NYB, THREADS, 0, stream>>>(
        validIn, confIn, posIn, yawIn, typeIn, out);
}